// Round 1
// baseline (1780.976 us; speedup 1.0000x reference)
//
#include <hip/hip_runtime.h>
#include <hip/hip_bf16.h>

// CANLayer: two sparse-attention convs (lower/upper) + linear skip, relu.
// Round 1: correctness-first fp32 pipeline.
//   K1 gemm3   : xm_low = x@W_low ; xm_up = x@W_up ; acc = x@W_lin*EPS
//   K2 att     : a[i]=xm[i]·att[:256], b[i]=xm[i]·att[256:]  (per conv)
//   K3 edge    : ev[e]=exp(elu(a[tgt]+b[src])*val[e]); s[tgt]+=ev  (atomic)
//   K4 spmm    : acc[tgt] += (ev/s[tgt]) * xm[src]             (atomic)
//   K5 relu    : out = relu(acc)
// softmax max-subtraction skipped: mathematically invariant, and
// v = elu(a+b)*val is bounded in (-1, ~4) so exp never overflows.

constexpr int N_NODES = 50000;
constexpr int N_EDGES = 800000;
constexpr int D = 256;
constexpr float EPSV = 1.0f + 1e-06f;

// ---------------- GEMM: C[M][256] = A[M][256] @ W[256][256] * scale ----------
// BM=64, BN=64, BK=16, 256 threads, 4x4 microtile per thread.
__global__ __launch_bounds__(256) void gemm3_kernel(
    const float* __restrict__ A,
    const float* __restrict__ W0, const float* __restrict__ W1, const float* __restrict__ W2,
    float* __restrict__ C0, float* __restrict__ C1, float* __restrict__ C2, int M)
{
    const int wz = blockIdx.z;
    const float* __restrict__ W = (wz == 0) ? W0 : (wz == 1) ? W1 : W2;
    float* __restrict__ C = (wz == 0) ? C0 : (wz == 1) ? C1 : C2;
    const float scale = (wz == 2) ? EPSV : 1.0f;

    __shared__ float As[16][65];   // [k][m], padded to kill write conflicts
    __shared__ float Ws[16][64];   // [k][n]

    const int tid = threadIdx.x;
    const int tx = tid & 15, ty = tid >> 4;
    const int bm = blockIdx.x * 64;
    const int bn = blockIdx.y * 64;

    // A-tile load mapping: row = tid/4 (0..63), 4 consecutive cols
    const int arow = tid >> 2, acol = (tid & 3) * 4;
    // W-tile load mapping: row = tid/16 (0..15), 16B per thread
    const int wrow = tid >> 4, wcol = (tid & 15) * 4;

    float acc[4][4] = {};

    for (int kt = 0; kt < 256; kt += 16) {
        float4 av = make_float4(0.f, 0.f, 0.f, 0.f);
        if (bm + arow < M)
            av = *reinterpret_cast<const float4*>(&A[(size_t)(bm + arow) * D + kt + acol]);
        As[acol + 0][arow] = av.x;
        As[acol + 1][arow] = av.y;
        As[acol + 2][arow] = av.z;
        As[acol + 3][arow] = av.w;

        float4 wv = *reinterpret_cast<const float4*>(&W[(size_t)(kt + wrow) * D + bn + wcol]);
        *reinterpret_cast<float4*>(&Ws[wrow][wcol]) = wv;

        __syncthreads();
        #pragma unroll
        for (int kk = 0; kk < 16; ++kk) {
            float ar[4], br[4];
            #pragma unroll
            for (int i = 0; i < 4; ++i) ar[i] = As[kk][ty * 4 + i];
            #pragma unroll
            for (int j = 0; j < 4; ++j) br[j] = Ws[kk][tx * 4 + j];
            #pragma unroll
            for (int i = 0; i < 4; ++i)
                #pragma unroll
                for (int j = 0; j < 4; ++j)
                    acc[i][j] += ar[i] * br[j];
        }
        __syncthreads();
    }

    #pragma unroll
    for (int i = 0; i < 4; ++i) {
        int r = bm + ty * 4 + i;
        if (r < M) {
            float4 o = make_float4(acc[i][0] * scale, acc[i][1] * scale,
                                   acc[i][2] * scale, acc[i][3] * scale);
            *reinterpret_cast<float4*>(&C[(size_t)r * D + bn + tx * 4]) = o;
        }
    }
}

// ---------------- per-node attention scalars (one wave per node) -------------
__global__ __launch_bounds__(256) void att_kernel(
    const float* __restrict__ xm, const float* __restrict__ att,
    float* __restrict__ a, float* __restrict__ b, int n)
{
    int node = (int)((blockIdx.x * 256 + threadIdx.x) >> 6);
    int lane = threadIdx.x & 63;
    if (node >= n) return;
    const float* row = xm + (size_t)node * D;
    float sa = 0.f, sb = 0.f;
    #pragma unroll
    for (int k = 0; k < 4; ++k) {
        float xv = row[lane + 64 * k];
        sa += xv * att[lane + 64 * k];
        sb += xv * att[D + lane + 64 * k];
    }
    #pragma unroll
    for (int off = 32; off; off >>= 1) {
        sa += __shfl_down(sa, off);
        sb += __shfl_down(sb, off);
    }
    if (lane == 0) { a[node] = sa; b[node] = sb; }
}

// ---------------- edge scores + softmax denominator --------------------------
__global__ __launch_bounds__(256) void edge_kernel(
    const int* __restrict__ idx, const float* __restrict__ vals,
    const float* __restrict__ a, const float* __restrict__ b,
    float* __restrict__ ev, float* __restrict__ s)
{
    int e = blockIdx.x * 256 + threadIdx.x;
    if (e >= N_EDGES) return;
    int tgt = idx[e];
    int src = idx[N_EDGES + e];
    float x = a[tgt] + b[src];
    float sc = (x > 0.f) ? x : (expf(x) - 1.f);   // elu, alpha=1
    float v = sc * vals[e];
    float evv = expf(v);                           // no max-sub needed (bounded)
    ev[e] = evv;
    atomicAdd(&s[tgt], evv);
}

// ---------------- SpMM scatter: one wave per edge ----------------------------
__global__ __launch_bounds__(256) void spmm_kernel(
    const int* __restrict__ idx, const float* __restrict__ ev,
    const float* __restrict__ s, const float* __restrict__ xm,
    float* __restrict__ acc)
{
    int e = (int)((blockIdx.x * 256 + threadIdx.x) >> 6);
    int lane = threadIdx.x & 63;
    if (e >= N_EDGES) return;
    int tgt = idx[e];
    int src = idx[N_EDGES + e];
    float w = ev[e] / s[tgt];
    const float* row = xm + (size_t)src * D;
    float* orow = acc + (size_t)tgt * D;
    #pragma unroll
    for (int k = 0; k < 4; ++k)
        atomicAdd(&orow[lane + 64 * k], w * row[lane + 64 * k]);
}

// ---------------- final relu -------------------------------------------------
__global__ __launch_bounds__(256) void relu_kernel(
    const float* __restrict__ acc, float* __restrict__ out, int n4)
{
    int i = blockIdx.x * 256 + threadIdx.x;
    if (i >= n4) return;
    float4 v = reinterpret_cast<const float4*>(acc)[i];
    v.x = fmaxf(v.x, 0.f); v.y = fmaxf(v.y, 0.f);
    v.z = fmaxf(v.z, 0.f); v.w = fmaxf(v.w, 0.f);
    reinterpret_cast<float4*>(out)[i] = v;
}

extern "C" void kernel_launch(void* const* d_in, const int* in_sizes, int n_in,
                              void* d_out, int out_size, void* d_ws, size_t ws_size,
                              hipStream_t stream)
{
    (void)in_sizes; (void)n_in; (void)out_size; (void)ws_size;
    const float* x        = (const float*)d_in[0];
    const int*   low_idx  = (const int*)  d_in[1];
    const float* low_vals = (const float*)d_in[2];
    const int*   up_idx   = (const int*)  d_in[3];
    const float* up_vals  = (const float*)d_in[4];
    const float* W_lower  = (const float*)d_in[5];
    const float* att_low  = (const float*)d_in[6];
    const float* W_upper  = (const float*)d_in[7];
    const float* att_up   = (const float*)d_in[8];
    const float* W_lin    = (const float*)d_in[9];
    float* out = (float*)d_out;

    char* ws = (char*)d_ws;
    size_t off = 0;
    auto alloc = [&](size_t bytes) {
        void* p = ws + off;
        off += (bytes + 255) & ~(size_t)255;
        return p;
    };
    float* acc    = (float*)alloc((size_t)N_NODES * D * 4);  // starts as xw
    float* xm_low = (float*)alloc((size_t)N_NODES * D * 4);
    float* xm_up  = (float*)alloc((size_t)N_NODES * D * 4);
    float* a_low  = (float*)alloc(N_NODES * 4);
    float* b_low  = (float*)alloc(N_NODES * 4);
    float* a_up   = (float*)alloc(N_NODES * 4);
    float* b_up   = (float*)alloc(N_NODES * 4);
    float* s_both = (float*)alloc(2 * N_NODES * 4);          // s_low | s_up
    float* s_low  = s_both;
    float* s_up   = s_both + N_NODES;
    float* ev_low = (float*)alloc(N_EDGES * 4);
    float* ev_up  = (float*)alloc(N_EDGES * 4);

    // zero softmax denominators (ws is poisoned before every timed call)
    hipMemsetAsync(s_both, 0, 2 * N_NODES * 4, stream);

    // 1) three GEMMs
    dim3 ggrid((N_NODES + 63) / 64, D / 64, 3);
    gemm3_kernel<<<ggrid, 256, 0, stream>>>(x, W_lower, W_upper, W_lin,
                                            xm_low, xm_up, acc, N_NODES);

    // 2) attention scalars
    int ablocks = (N_NODES + 3) / 4;
    att_kernel<<<ablocks, 256, 0, stream>>>(xm_low, att_low, a_low, b_low, N_NODES);
    att_kernel<<<ablocks, 256, 0, stream>>>(xm_up,  att_up,  a_up,  b_up,  N_NODES);

    // 3) edge scores + denominators
    int eblocks = (N_EDGES + 255) / 256;
    edge_kernel<<<eblocks, 256, 0, stream>>>(low_idx, low_vals, a_low, b_low, ev_low, s_low);
    edge_kernel<<<eblocks, 256, 0, stream>>>(up_idx,  up_vals,  a_up,  b_up,  ev_up,  s_up);

    // 4) SpMM scatter into acc
    int sblocks = (N_EDGES + 3) / 4;
    spmm_kernel<<<sblocks, 256, 0, stream>>>(low_idx, ev_low, s_low, xm_low, acc);
    spmm_kernel<<<sblocks, 256, 0, stream>>>(up_idx,  ev_up,  s_up,  xm_up,  acc);

    // 5) relu
    int n4 = N_NODES * D / 4;
    relu_kernel<<<(n4 + 255) / 256, 256, 0, stream>>>(acc, out, n4);
}

// Round 3
// 884.518 us; speedup vs baseline: 2.0135x; 2.0135x over previous
//
#include <hip/hip_runtime.h>
#include <hip/hip_bf16.h>

// CANLayer round 2b (resubmit after infra failure): CSR-gather pipeline.
//   K1 gemm3   : xm_low = x@W_low ; xm_up = x@W_up ; out = x@W_lin*EPS
//   K2 att     : a[i]=xm[i]·att[:256], b[i]=xm[i]·att[256:]  (per conv)
//   K3 hist    : cnt[tgt]++ for both convs
//   K4 scan    : ro = exclusive_scan(cnt)        (one block per conv)
//   K5 scatter : csr[(ro[tgt]+cur[tgt]++)] = (src, val)
//   K6 gather  : per-node wave: s = sum(ev), acc = sum(ev/s * xm[src]) for
//                both convs; out = relu(acc + out)   (out held x@W_lin*EPS)
// softmax max-subtraction skipped: invariant, v bounded in (-1,~3).

constexpr int N_NODES = 50000;
constexpr int N_EDGES = 800000;
constexpr int D = 256;
constexpr float EPSV = 1.0f + 1e-06f;

// ---------------- GEMM: C[M][256] = A[M][256] @ W[256][256] * scale ----------
__global__ __launch_bounds__(256) void gemm3_kernel(
    const float* __restrict__ A,
    const float* __restrict__ W0, const float* __restrict__ W1, const float* __restrict__ W2,
    float* __restrict__ C0, float* __restrict__ C1, float* __restrict__ C2, int M)
{
    const int wz = blockIdx.z;
    const float* __restrict__ W = (wz == 0) ? W0 : (wz == 1) ? W1 : W2;
    float* __restrict__ C = (wz == 0) ? C0 : (wz == 1) ? C1 : C2;
    const float scale = (wz == 2) ? EPSV : 1.0f;

    __shared__ float As[16][65];
    __shared__ float Ws[16][64];

    const int tid = threadIdx.x;
    const int tx = tid & 15, ty = tid >> 4;
    const int bm = blockIdx.x * 64;
    const int bn = blockIdx.y * 64;

    const int arow = tid >> 2, acol = (tid & 3) * 4;
    const int wrow = tid >> 4, wcol = (tid & 15) * 4;

    float acc[4][4] = {};

    for (int kt = 0; kt < 256; kt += 16) {
        float4 av = make_float4(0.f, 0.f, 0.f, 0.f);
        if (bm + arow < M)
            av = *reinterpret_cast<const float4*>(&A[(size_t)(bm + arow) * D + kt + acol]);
        As[acol + 0][arow] = av.x;
        As[acol + 1][arow] = av.y;
        As[acol + 2][arow] = av.z;
        As[acol + 3][arow] = av.w;

        float4 wv = *reinterpret_cast<const float4*>(&W[(size_t)(kt + wrow) * D + bn + wcol]);
        *reinterpret_cast<float4*>(&Ws[wrow][wcol]) = wv;

        __syncthreads();
        #pragma unroll
        for (int kk = 0; kk < 16; ++kk) {
            float ar[4], br[4];
            #pragma unroll
            for (int i = 0; i < 4; ++i) ar[i] = As[kk][ty * 4 + i];
            #pragma unroll
            for (int j = 0; j < 4; ++j) br[j] = Ws[kk][tx * 4 + j];
            #pragma unroll
            for (int i = 0; i < 4; ++i)
                #pragma unroll
                for (int j = 0; j < 4; ++j)
                    acc[i][j] += ar[i] * br[j];
        }
        __syncthreads();
    }

    #pragma unroll
    for (int i = 0; i < 4; ++i) {
        int r = bm + ty * 4 + i;
        if (r < M) {
            float4 o = make_float4(acc[i][0] * scale, acc[i][1] * scale,
                                   acc[i][2] * scale, acc[i][3] * scale);
            *reinterpret_cast<float4*>(&C[(size_t)r * D + bn + tx * 4]) = o;
        }
    }
}

// ---------------- per-node attention scalars (one wave per node) -------------
__global__ __launch_bounds__(256) void att_kernel(
    const float* __restrict__ xm, const float* __restrict__ att,
    float* __restrict__ a, float* __restrict__ b, int n)
{
    int node = (int)((blockIdx.x * 256 + threadIdx.x) >> 6);
    int lane = threadIdx.x & 63;
    if (node >= n) return;
    const float* row = xm + (size_t)node * D;
    float sa = 0.f, sb = 0.f;
    #pragma unroll
    for (int k = 0; k < 4; ++k) {
        float xv = row[lane + 64 * k];
        sa += xv * att[lane + 64 * k];
        sb += xv * att[D + lane + 64 * k];
    }
    #pragma unroll
    for (int off = 32; off; off >>= 1) {
        sa += __shfl_down(sa, off);
        sb += __shfl_down(sb, off);
    }
    if (lane == 0) { a[node] = sa; b[node] = sb; }
}

// ---------------- CSR build: histogram ---------------------------------------
__global__ __launch_bounds__(256) void hist_kernel(
    const int* __restrict__ il, const int* __restrict__ iu,
    int* __restrict__ cl, int* __restrict__ cu)
{
    int e = blockIdx.x * 256 + threadIdx.x;
    if (e >= N_EDGES) return;
    atomicAdd(&cl[il[e]], 1);
    atomicAdd(&cu[iu[e]], 1);
}

// ---------------- CSR build: exclusive scan (one block per conv) -------------
__global__ __launch_bounds__(1024) void scan_kernel(
    const int* __restrict__ cnt0, int* __restrict__ ro0,
    const int* __restrict__ cnt1, int* __restrict__ ro1, int n)
{
    const int* cnt = blockIdx.x == 0 ? cnt0 : cnt1;
    int* ro = blockIdx.x == 0 ? ro0 : ro1;
    __shared__ int sm[1024];
    int tid = threadIdx.x;
    int run = 0;
    for (int base = 0; base < n; base += 1024) {
        int v = (base + tid < n) ? cnt[base + tid] : 0;
        sm[tid] = v;
        __syncthreads();
        #pragma unroll
        for (int off = 1; off < 1024; off <<= 1) {
            int t = (tid >= off) ? sm[tid - off] : 0;
            __syncthreads();
            sm[tid] += t;
            __syncthreads();
        }
        if (base + tid < n) ro[base + tid] = run + sm[tid] - v;  // exclusive
        run += sm[1023];
        __syncthreads();
    }
    if (tid == 0) ro[n] = run;
}

// ---------------- CSR build: scatter ------------------------------------------
__global__ __launch_bounds__(256) void scatter_kernel(
    const int* __restrict__ il, const float* __restrict__ vl,
    const int* __restrict__ rol, int* __restrict__ curl,
    int* __restrict__ csl, float* __restrict__ cvl,
    const int* __restrict__ iu, const float* __restrict__ vu,
    const int* __restrict__ rou, int* __restrict__ curu,
    int* __restrict__ csu, float* __restrict__ cvu)
{
    int e = blockIdx.x * 256 + threadIdx.x;
    if (e >= N_EDGES) return;
    int tl = il[e];
    int pl = rol[tl] + atomicAdd(&curl[tl], 1);
    csl[pl] = il[N_EDGES + e];
    cvl[pl] = vl[e];
    int tu = iu[e];
    int pu = rou[tu] + atomicAdd(&curu[tu], 1);
    csu[pu] = iu[N_EDGES + e];
    cvu[pu] = vu[e];
}

// ---------------- fused gather + softmax + skip + relu ------------------------
__device__ __forceinline__ float wave_sum(float v) {
    #pragma unroll
    for (int off = 32; off; off >>= 1) v += __shfl_xor(v, off);
    return v;
}

__device__ __forceinline__ void conv_accum(
    int node, int lane,
    const int* __restrict__ ro, const int* __restrict__ cs, const float* __restrict__ cv,
    const float* __restrict__ a, const float* __restrict__ b,
    const float4* __restrict__ xm, float4& acc)
{
    int rs = ro[node], re = ro[node + 1];
    int deg = re - rs;
    if (deg <= 0) return;
    float ai = a[node];
    if (deg <= 64) {
        float evl = 0.f; int srcl = 0;
        if (lane < deg) {
            srcl = cs[rs + lane];
            float xv = ai + b[srcl];
            float sc = (xv > 0.f) ? xv : (expf(xv) - 1.f);
            evl = expf(sc * cv[rs + lane]);
        }
        float invs = 1.f / wave_sum(evl);
        for (int t = 0; t < deg; ++t) {
            float w = __shfl(evl, t) * invs;
            int si = __shfl(srcl, t);
            float4 v = xm[(size_t)si * 64 + lane];
            acc.x += w * v.x; acc.y += w * v.y; acc.z += w * v.z; acc.w += w * v.w;
        }
    } else {
        float s = 0.f;
        for (int c = rs; c < re; c += 64) {
            int m = min(64, re - c);
            float evl = 0.f;
            if (lane < m) {
                int si = cs[c + lane];
                float xv = ai + b[si];
                float sc = (xv > 0.f) ? xv : (expf(xv) - 1.f);
                evl = expf(sc * cv[c + lane]);
            }
            s += wave_sum(evl);
        }
        float invs = 1.f / s;
        for (int c = rs; c < re; c += 64) {
            int m = min(64, re - c);
            float evl = 0.f; int srcl = 0;
            if (lane < m) {
                srcl = cs[c + lane];
                float xv = ai + b[srcl];
                float sc = (xv > 0.f) ? xv : (expf(xv) - 1.f);
                evl = expf(sc * cv[c + lane]);
            }
            for (int t = 0; t < m; ++t) {
                float w = __shfl(evl, t) * invs;
                int si = __shfl(srcl, t);
                float4 v = xm[(size_t)si * 64 + lane];
                acc.x += w * v.x; acc.y += w * v.y; acc.z += w * v.z; acc.w += w * v.w;
            }
        }
    }
}

__global__ __launch_bounds__(256) void gather_kernel(
    const int* __restrict__ rol, const int* __restrict__ csl, const float* __restrict__ cvl,
    const float* __restrict__ al, const float* __restrict__ bl, const float4* __restrict__ xml,
    const int* __restrict__ rou, const int* __restrict__ csu, const float* __restrict__ cvu,
    const float* __restrict__ au, const float* __restrict__ bu, const float4* __restrict__ xmu,
    float4* __restrict__ out)
{
    int node = (int)((blockIdx.x * 256 + threadIdx.x) >> 6);
    int lane = threadIdx.x & 63;
    if (node >= N_NODES) return;
    float4 acc = make_float4(0.f, 0.f, 0.f, 0.f);
    conv_accum(node, lane, rol, csl, cvl, al, bl, xml, acc);
    conv_accum(node, lane, rou, csu, cvu, au, bu, xmu, acc);
    float4 xw = out[(size_t)node * 64 + lane];
    acc.x = fmaxf(acc.x + xw.x, 0.f);
    acc.y = fmaxf(acc.y + xw.y, 0.f);
    acc.z = fmaxf(acc.z + xw.z, 0.f);
    acc.w = fmaxf(acc.w + xw.w, 0.f);
    out[(size_t)node * 64 + lane] = acc;
}

extern "C" void kernel_launch(void* const* d_in, const int* in_sizes, int n_in,
                              void* d_out, int out_size, void* d_ws, size_t ws_size,
                              hipStream_t stream)
{
    (void)in_sizes; (void)n_in; (void)out_size; (void)ws_size;
    const float* x        = (const float*)d_in[0];
    const int*   low_idx  = (const int*)  d_in[1];
    const float* low_vals = (const float*)d_in[2];
    const int*   up_idx   = (const int*)  d_in[3];
    const float* up_vals  = (const float*)d_in[4];
    const float* W_lower  = (const float*)d_in[5];
    const float* att_low  = (const float*)d_in[6];
    const float* W_upper  = (const float*)d_in[7];
    const float* att_up   = (const float*)d_in[8];
    const float* W_lin    = (const float*)d_in[9];
    float* out = (float*)d_out;

    char* ws = (char*)d_ws;
    size_t off = 0;
    auto alloc = [&](size_t bytes) {
        void* p = ws + off;
        off += (bytes + 255) & ~(size_t)255;
        return p;
    };
    float* xm_low = (float*)alloc((size_t)N_NODES * D * 4);
    float* xm_up  = (float*)alloc((size_t)N_NODES * D * 4);
    float* a_low  = (float*)alloc(N_NODES * 4);
    float* b_low  = (float*)alloc(N_NODES * 4);
    float* a_up   = (float*)alloc(N_NODES * 4);
    float* b_up   = (float*)alloc(N_NODES * 4);
    // contiguous zero block: cnt_low | cnt_up | cur_low | cur_up
    int* zero_blk = (int*)alloc(4 * N_NODES * 4);
    int* cnt_low = zero_blk;
    int* cnt_up  = zero_blk + N_NODES;
    int* cur_low = zero_blk + 2 * N_NODES;
    int* cur_up  = zero_blk + 3 * N_NODES;
    int* ro_low  = (int*)alloc((N_NODES + 1) * 4);
    int* ro_up   = (int*)alloc((N_NODES + 1) * 4);
    int*   cs_low = (int*)  alloc((size_t)N_EDGES * 4);
    float* cv_low = (float*)alloc((size_t)N_EDGES * 4);
    int*   cs_up  = (int*)  alloc((size_t)N_EDGES * 4);
    float* cv_up  = (float*)alloc((size_t)N_EDGES * 4);

    hipMemsetAsync(zero_blk, 0, 4 * N_NODES * 4, stream);

    // 1) three GEMMs (skip path written straight into d_out)
    dim3 ggrid((N_NODES + 63) / 64, D / 64, 3);
    gemm3_kernel<<<ggrid, 256, 0, stream>>>(x, W_lower, W_upper, W_lin,
                                            xm_low, xm_up, out, N_NODES);

    // 2) attention scalars
    int ablocks = (N_NODES + 3) / 4;
    att_kernel<<<ablocks, 256, 0, stream>>>(xm_low, att_low, a_low, b_low, N_NODES);
    att_kernel<<<ablocks, 256, 0, stream>>>(xm_up,  att_up,  a_up,  b_up,  N_NODES);

    // 3) CSR build
    int eblocks = (N_EDGES + 255) / 256;
    hist_kernel<<<eblocks, 256, 0, stream>>>(low_idx, up_idx, cnt_low, cnt_up);
    scan_kernel<<<2, 1024, 0, stream>>>(cnt_low, ro_low, cnt_up, ro_up, N_NODES);
    scatter_kernel<<<eblocks, 256, 0, stream>>>(
        low_idx, low_vals, ro_low, cur_low, cs_low, cv_low,
        up_idx,  up_vals,  ro_up,  cur_up,  cs_up,  cv_up);

    // 4) fused gather + softmax + skip + relu
    int gblocks = (N_NODES + 3) / 4;
    gather_kernel<<<gblocks, 256, 0, stream>>>(
        ro_low, cs_low, cv_low, a_low, b_low, (const float4*)xm_low,
        ro_up,  cs_up,  cv_up,  a_up,  b_up,  (const float4*)xm_up,
        (float4*)out);
}

// Round 4
// 538.281 us; speedup vs baseline: 3.3086x; 1.6432x over previous
//
#include <hip/hip_runtime.h>
#include <hip/hip_bf16.h>

// CANLayer round 4: bf16-MFMA GEMM + parallel scan + bf16 packed gather.
//   K0a cvt_x   : xb = bf16(x)
//   K0b cvt_w   : wbT[z][n][k] = bf16(W_z[k][n])   (transposed, z=0..2)
//   K1  gemm    : xm_low/up (bf16) = xb@W ; out(fp32) = xb@W_lin*EPS   [MFMA]
//   K2  att     : a[i]=xm[i]·att[:256], b[i]=xm[i]·att[256:]  (bf16 xm)
//   K3  hist    : cnt[tgt]++ for both convs
//   K4  scan    : 3-phase parallel exclusive scan -> ro
//   K5  scatter : edg[(ro[tgt]+cur[tgt]++)] = {src, val}   (packed int2)
//   K6  gather  : per-node wave softmax-gather (bf16 rows), + skip + relu
// softmax max-subtraction skipped: invariant, v bounded in (-1,~3).

constexpr int N_NODES = 50000;
constexpr int N_EDGES = 800000;
constexpr int D = 256;
constexpr float EPSV = 1.0f + 1e-06f;

typedef __attribute__((ext_vector_type(8))) short short8;
typedef __attribute__((ext_vector_type(4))) float f32x4;

__device__ __forceinline__ unsigned short f2bf(float f) {
    unsigned int b = __float_as_uint(f);
    unsigned int r = (b + 0x7FFFu + ((b >> 16) & 1u)) >> 16;   // RNE
    return (unsigned short)r;
}
__device__ __forceinline__ float bf2f(unsigned short u) {
    return __uint_as_float(((unsigned int)u) << 16);
}

// ---------------- convert x to bf16 ------------------------------------------
__global__ __launch_bounds__(256) void cvt_x_kernel(
    const float4* __restrict__ x, ushort4* __restrict__ xb, int n4)
{
    int i = blockIdx.x * 256 + threadIdx.x;
    if (i >= n4) return;
    float4 v = x[i];
    ushort4 o;
    o.x = f2bf(v.x); o.y = f2bf(v.y); o.z = f2bf(v.z); o.w = f2bf(v.w);
    xb[i] = o;
}

// ---------------- convert + transpose weights --------------------------------
__global__ __launch_bounds__(256) void cvt_w_kernel(
    const float* __restrict__ W0, const float* __restrict__ W1,
    const float* __restrict__ W2, unsigned short* __restrict__ wbT)
{
    int z = blockIdx.y;
    const float* W = (z == 0) ? W0 : (z == 1) ? W1 : W2;
    int n = blockIdx.x;           // output row of wbT = column of W
    int k = threadIdx.x;
    wbT[(size_t)z * 65536 + (size_t)n * 256 + k] = f2bf(W[(size_t)k * 256 + n]);
}

// ---------------- MFMA GEMM: BM=128, BN=64, 4 waves, no LDS ------------------
// frag maps (verified layouts): A: lane l elem i -> A[l%16][8*(l/16)+i]
//                               B: lane l elem i -> B[8*(l/16)+i][l%16]
//                               C: lane l reg r  -> C[4*(l/16)+r][l%16]
__global__ __launch_bounds__(256) void gemm_mfma_kernel(
    const unsigned short* __restrict__ xb, const unsigned short* __restrict__ wbT,
    unsigned short* __restrict__ xml, unsigned short* __restrict__ xmu,
    float* __restrict__ out, int M)
{
    const int wz = blockIdx.z;
    const int tid = threadIdx.x;
    const int w = tid >> 6, lane = tid & 63;
    const int r16 = lane & 15, g = lane >> 4;
    const int m0 = blockIdx.x * 128 + w * 32;
    const int n0 = blockIdx.y * 64;
    const unsigned short* wb = wbT + (size_t)wz * 65536;

    const int ar0 = min(m0 + r16, M - 1);
    const int ar1 = min(m0 + 16 + r16, M - 1);
    const unsigned short* pa0 = xb + (size_t)ar0 * 256 + 8 * g;
    const unsigned short* pa1 = xb + (size_t)ar1 * 256 + 8 * g;
    const unsigned short* pb  = wb + (size_t)(n0 + r16) * 256 + 8 * g;

    f32x4 acc[2][4];
    #pragma unroll
    for (int mf = 0; mf < 2; ++mf)
        #pragma unroll
        for (int nf = 0; nf < 4; ++nf)
            acc[mf][nf] = (f32x4){0.f, 0.f, 0.f, 0.f};

    #pragma unroll
    for (int kt = 0; kt < 256; kt += 32) {
        short8 a0 = *reinterpret_cast<const short8*>(pa0 + kt);
        short8 a1 = *reinterpret_cast<const short8*>(pa1 + kt);
        #pragma unroll
        for (int nf = 0; nf < 4; ++nf) {
            short8 bf = *reinterpret_cast<const short8*>(pb + (size_t)nf * 16 * 256 + kt);
            acc[0][nf] = __builtin_amdgcn_mfma_f32_16x16x32_bf16(a0, bf, acc[0][nf], 0, 0, 0);
            acc[1][nf] = __builtin_amdgcn_mfma_f32_16x16x32_bf16(a1, bf, acc[1][nf], 0, 0, 0);
        }
    }

    if (wz < 2) {
        unsigned short* dst = wz ? xmu : xml;
        #pragma unroll
        for (int mf = 0; mf < 2; ++mf)
            #pragma unroll
            for (int r = 0; r < 4; ++r) {
                int row = m0 + mf * 16 + g * 4 + r;
                if (row < M) {
                    #pragma unroll
                    for (int nf = 0; nf < 4; ++nf)
                        dst[(size_t)row * 256 + n0 + nf * 16 + r16] = f2bf(acc[mf][nf][r]);
                }
            }
    } else {
        #pragma unroll
        for (int mf = 0; mf < 2; ++mf)
            #pragma unroll
            for (int r = 0; r < 4; ++r) {
                int row = m0 + mf * 16 + g * 4 + r;
                if (row < M) {
                    #pragma unroll
                    for (int nf = 0; nf < 4; ++nf)
                        out[(size_t)row * 256 + n0 + nf * 16 + r16] = acc[mf][nf][r] * EPSV;
                }
            }
    }
}

// ---------------- per-node attention scalars (bf16 xm, one wave/node) --------
__global__ __launch_bounds__(256) void att_kernel(
    const unsigned short* __restrict__ xm, const float* __restrict__ att,
    float* __restrict__ a, float* __restrict__ b, int n)
{
    int node = (int)((blockIdx.x * 256 + threadIdx.x) >> 6);
    int lane = threadIdx.x & 63;
    if (node >= n) return;
    ushort4 uv = *reinterpret_cast<const ushort4*>(xm + (size_t)node * 256 + lane * 4);
    float x0 = bf2f(uv.x), x1 = bf2f(uv.y), x2 = bf2f(uv.z), x3 = bf2f(uv.w);
    int o = lane * 4;
    float sa = x0 * att[o] + x1 * att[o + 1] + x2 * att[o + 2] + x3 * att[o + 3];
    float sb = x0 * att[D + o] + x1 * att[D + o + 1] + x2 * att[D + o + 2] + x3 * att[D + o + 3];
    #pragma unroll
    for (int off = 32; off; off >>= 1) {
        sa += __shfl_down(sa, off);
        sb += __shfl_down(sb, off);
    }
    if (lane == 0) { a[node] = sa; b[node] = sb; }
}

// ---------------- CSR build: histogram ---------------------------------------
__global__ __launch_bounds__(256) void hist_kernel(
    const int* __restrict__ il, const int* __restrict__ iu,
    int* __restrict__ cl, int* __restrict__ cu)
{
    int e = blockIdx.x * 256 + threadIdx.x;
    if (e >= N_EDGES) return;
    atomicAdd(&cl[il[e]], 1);
    atomicAdd(&cu[iu[e]], 1);
}

// ---------------- 3-phase scan -----------------------------------------------
__global__ __launch_bounds__(1024) void scan_local_kernel(
    const int* __restrict__ cnt0, int* __restrict__ ro0,
    const int* __restrict__ cnt1, int* __restrict__ ro1,
    int* __restrict__ bsum, int n)
{
    int c = blockIdx.y;
    const int* cnt = c ? cnt1 : cnt0;
    int* ro = c ? ro1 : ro0;
    __shared__ int sm[1024];
    int tid = threadIdx.x;
    int i = blockIdx.x * 1024 + tid;
    int v = (i < n) ? cnt[i] : 0;
    sm[tid] = v;
    __syncthreads();
    #pragma unroll
    for (int off = 1; off < 1024; off <<= 1) {
        int t = (tid >= off) ? sm[tid - off] : 0;
        __syncthreads();
        sm[tid] += t;
        __syncthreads();
    }
    if (i < n) ro[i] = sm[tid] - v;                 // local exclusive
    if (tid == 1023) bsum[c * 64 + blockIdx.x] = sm[1023];
}

__global__ __launch_bounds__(128) void scan_bsum_kernel(int* __restrict__ bsum, int nb)
{
    int c = threadIdx.x >> 6, lane = threadIdx.x & 63;
    int v = (lane < nb) ? bsum[c * 64 + lane] : 0;
    int orig = v;
    #pragma unroll
    for (int off = 1; off < 64; off <<= 1) {
        int t = __shfl_up(v, off);
        if (lane >= off) v += t;
    }
    if (lane < nb) bsum[c * 64 + lane] = v - orig;  // exclusive block offsets
}

__global__ __launch_bounds__(256) void scan_apply_kernel(
    int* __restrict__ ro0, int* __restrict__ ro1,
    const int* __restrict__ bsum, int n)
{
    int c = blockIdx.y;
    int* ro = c ? ro1 : ro0;
    int i = blockIdx.x * 256 + threadIdx.x;
    if (i < n) ro[i] += bsum[c * 64 + (i >> 10)];
    if (i == 0) ro[n] = N_EDGES;
}

// ---------------- CSR build: scatter (packed int2) ---------------------------
__global__ __launch_bounds__(256) void scatter_kernel(
    const int* __restrict__ il, const float* __restrict__ vl,
    const int* __restrict__ rol, int* __restrict__ curl, int2* __restrict__ egl,
    const int* __restrict__ iu, const float* __restrict__ vu,
    const int* __restrict__ rou, int* __restrict__ curu, int2* __restrict__ egu)
{
    int e = blockIdx.x * 256 + threadIdx.x;
    if (e >= N_EDGES) return;
    int tl = il[e];
    int pl = rol[tl] + atomicAdd(&curl[tl], 1);
    int2 p; p.x = il[N_EDGES + e]; p.y = __float_as_int(vl[e]);
    egl[pl] = p;
    int tu = iu[e];
    int pu = rou[tu] + atomicAdd(&curu[tu], 1);
    int2 q; q.x = iu[N_EDGES + e]; q.y = __float_as_int(vu[e]);
    egu[pu] = q;
}

// ---------------- fused gather + softmax + skip + relu -----------------------
__device__ __forceinline__ float wave_sum(float v) {
    #pragma unroll
    for (int off = 32; off; off >>= 1) v += __shfl_xor(v, off);
    return v;
}

__device__ __forceinline__ void conv_accum(
    int node, int lane,
    const int* __restrict__ ro, const int2* __restrict__ eg,
    const float* __restrict__ a, const float* __restrict__ b,
    const unsigned short* __restrict__ xm, float4& acc)
{
    int rs = ro[node], re = ro[node + 1];
    int deg = re - rs;
    if (deg <= 0) return;
    float ai = a[node];
    if (deg <= 64) {
        float evl = 0.f; int srcl = 0;
        if (lane < deg) {
            int2 p = eg[rs + lane];
            srcl = p.x;
            float xv = ai + b[srcl];
            float sc = (xv > 0.f) ? xv : (expf(xv) - 1.f);
            evl = expf(sc * __int_as_float(p.y));
        }
        float invs = 1.f / wave_sum(evl);
        for (int t = 0; t < deg; ++t) {
            float w = __shfl(evl, t) * invs;
            int si = __shfl(srcl, t);
            ushort4 uv = *reinterpret_cast<const ushort4*>(xm + (size_t)si * 256 + lane * 4);
            acc.x += w * bf2f(uv.x); acc.y += w * bf2f(uv.y);
            acc.z += w * bf2f(uv.z); acc.w += w * bf2f(uv.w);
        }
    } else {
        float s = 0.f;
        for (int c = rs; c < re; c += 64) {
            int m = min(64, re - c);
            float evl = 0.f;
            if (lane < m) {
                int2 p = eg[c + lane];
                float xv = ai + b[p.x];
                float sc = (xv > 0.f) ? xv : (expf(xv) - 1.f);
                evl = expf(sc * __int_as_float(p.y));
            }
            s += wave_sum(evl);
        }
        float invs = 1.f / s;
        for (int c = rs; c < re; c += 64) {
            int m = min(64, re - c);
            float evl = 0.f; int srcl = 0;
            if (lane < m) {
                int2 p = eg[c + lane];
                srcl = p.x;
                float xv = ai + b[srcl];
                float sc = (xv > 0.f) ? xv : (expf(xv) - 1.f);
                evl = expf(sc * __int_as_float(p.y));
            }
            for (int t = 0; t < m; ++t) {
                float w = __shfl(evl, t) * invs;
                int si = __shfl(srcl, t);
                ushort4 uv = *reinterpret_cast<const ushort4*>(xm + (size_t)si * 256 + lane * 4);
                acc.x += w * bf2f(uv.x); acc.y += w * bf2f(uv.y);
                acc.z += w * bf2f(uv.z); acc.w += w * bf2f(uv.w);
            }
        }
    }
}

__global__ __launch_bounds__(256) void gather_kernel(
    const int* __restrict__ rol, const int2* __restrict__ egl,
    const float* __restrict__ al, const float* __restrict__ bl,
    const unsigned short* __restrict__ xml,
    const int* __restrict__ rou, const int2* __restrict__ egu,
    const float* __restrict__ au, const float* __restrict__ bu,
    const unsigned short* __restrict__ xmu,
    float4* __restrict__ out)
{
    int node = (int)((blockIdx.x * 256 + threadIdx.x) >> 6);
    int lane = threadIdx.x & 63;
    if (node >= N_NODES) return;
    float4 acc = make_float4(0.f, 0.f, 0.f, 0.f);
    conv_accum(node, lane, rol, egl, al, bl, xml, acc);
    conv_accum(node, lane, rou, egu, au, bu, xmu, acc);
    float4 xw = out[(size_t)node * 64 + lane];
    acc.x = fmaxf(acc.x + xw.x, 0.f);
    acc.y = fmaxf(acc.y + xw.y, 0.f);
    acc.z = fmaxf(acc.z + xw.z, 0.f);
    acc.w = fmaxf(acc.w + xw.w, 0.f);
    out[(size_t)node * 64 + lane] = acc;
}

extern "C" void kernel_launch(void* const* d_in, const int* in_sizes, int n_in,
                              void* d_out, int out_size, void* d_ws, size_t ws_size,
                              hipStream_t stream)
{
    (void)in_sizes; (void)n_in; (void)out_size; (void)ws_size;
    const float* x        = (const float*)d_in[0];
    const int*   low_idx  = (const int*)  d_in[1];
    const float* low_vals = (const float*)d_in[2];
    const int*   up_idx   = (const int*)  d_in[3];
    const float* up_vals  = (const float*)d_in[4];
    const float* W_lower  = (const float*)d_in[5];
    const float* att_low  = (const float*)d_in[6];
    const float* W_upper  = (const float*)d_in[7];
    const float* att_up   = (const float*)d_in[8];
    const float* W_lin    = (const float*)d_in[9];
    float* out = (float*)d_out;

    char* ws = (char*)d_ws;
    size_t off = 0;
    auto alloc = [&](size_t bytes) {
        void* p = ws + off;
        off += (bytes + 255) & ~(size_t)255;
        return p;
    };
    unsigned short* xb     = (unsigned short*)alloc((size_t)N_NODES * D * 2);
    unsigned short* wbT    = (unsigned short*)alloc((size_t)3 * 256 * 256 * 2);
    unsigned short* xm_low = (unsigned short*)alloc((size_t)N_NODES * D * 2);
    unsigned short* xm_up  = (unsigned short*)alloc((size_t)N_NODES * D * 2);
    float* a_low  = (float*)alloc(N_NODES * 4);
    float* b_low  = (float*)alloc(N_NODES * 4);
    float* a_up   = (float*)alloc(N_NODES * 4);
    float* b_up   = (float*)alloc(N_NODES * 4);
    int* zero_blk = (int*)alloc(4 * N_NODES * 4);   // cnt_l | cnt_u | cur_l | cur_u
    int* cnt_low = zero_blk;
    int* cnt_up  = zero_blk + N_NODES;
    int* cur_low = zero_blk + 2 * N_NODES;
    int* cur_up  = zero_blk + 3 * N_NODES;
    int* ro_low  = (int*)alloc((N_NODES + 1) * 4);
    int* ro_up   = (int*)alloc((N_NODES + 1) * 4);
    int* bsum    = (int*)alloc(2 * 64 * 4);
    int2* eg_low = (int2*)alloc((size_t)N_EDGES * 8);
    int2* eg_up  = (int2*)alloc((size_t)N_EDGES * 8);

    hipMemsetAsync(zero_blk, 0, 4 * N_NODES * 4, stream);

    // 0) casts
    int n4 = N_NODES * D / 4;
    cvt_x_kernel<<<(n4 + 255) / 256, 256, 0, stream>>>(
        (const float4*)x, (ushort4*)xb, n4);
    dim3 wgrid(256, 3);
    cvt_w_kernel<<<wgrid, 256, 0, stream>>>(W_lower, W_upper, W_lin, wbT);

    // 1) MFMA GEMMs (skip path straight into d_out as fp32)
    dim3 ggrid((N_NODES + 127) / 128, D / 64, 3);
    gemm_mfma_kernel<<<ggrid, 256, 0, stream>>>(xb, wbT, xm_low, xm_up, out, N_NODES);

    // 2) attention scalars
    int ablocks = (N_NODES + 3) / 4;
    att_kernel<<<ablocks, 256, 0, stream>>>(xm_low, att_low, a_low, b_low, N_NODES);
    att_kernel<<<ablocks, 256, 0, stream>>>(xm_up,  att_up,  a_up,  b_up,  N_NODES);

    // 3) CSR build
    int eblocks = (N_EDGES + 255) / 256;
    hist_kernel<<<eblocks, 256, 0, stream>>>(low_idx, up_idx, cnt_low, cnt_up);
    dim3 sgrid((N_NODES + 1023) / 1024, 2);
    scan_local_kernel<<<sgrid, 1024, 0, stream>>>(cnt_low, ro_low, cnt_up, ro_up,
                                                  bsum, N_NODES);
    scan_bsum_kernel<<<1, 128, 0, stream>>>(bsum, (N_NODES + 1023) / 1024);
    dim3 agrid((N_NODES + 255) / 256, 2);
    scan_apply_kernel<<<agrid, 256, 0, stream>>>(ro_low, ro_up, bsum, N_NODES);
    scatter_kernel<<<eblocks, 256, 0, stream>>>(
        low_idx, low_vals, ro_low, cur_low, eg_low,
        up_idx,  up_vals,  ro_up,  cur_up,  eg_up);

    // 4) fused gather + softmax + skip + relu
    int gblocks = (N_NODES + 3) / 4;
    gather_kernel<<<gblocks, 256, 0, stream>>>(
        ro_low, eg_low, a_low, b_low, xm_low,
        ro_up,  eg_up,  a_up,  b_up,  xm_up,
        (float4*)out);
}

// Round 5
// 483.548 us; speedup vs baseline: 3.6831x; 1.1132x over previous
//
#include <hip/hip_runtime.h>
#include <hip/hip_bf16.h>

// CANLayer round 5: fused mega-GEMM (+att epilogue), rank-based CSR, MLP gather.
//   K0a cvt_x   : xb = bf16(x)
//   K0b cvt_w   : wbT[z][n][k] = bf16(W_z[k][n])   (transposed, z=0..2)
//   K1  gemmF   : per block (32 rows x all 256 cols x all 3 weights):
//                 xm_low/up (bf16), out = x@W_lin*EPS (fp32),
//                 a/b att scalars via in-block reduce          [MFMA]
//   K2  hist    : rank[e] = cnt[tgt]++  (atomic returns rank)
//   K3  scan    : 3-phase parallel exclusive scan -> ro
//   K4  scatter : eg[ro[tgt]+rank[e]] = {src, val}   (no atomics)
//   K5  gather  : per-node wave softmax-gather (bf16 rows, 2x unroll),
//                 + skip + relu
// softmax max-subtraction skipped: invariant, v bounded in (-1,~3).

constexpr int N_NODES = 50000;
constexpr int N_EDGES = 800000;
constexpr int D = 256;
constexpr float EPSV = 1.0f + 1e-06f;

typedef __attribute__((ext_vector_type(8))) short short8;
typedef __attribute__((ext_vector_type(4))) float f32x4;

__device__ __forceinline__ unsigned short f2bf(float f) {
    unsigned int b = __float_as_uint(f);
    unsigned int r = (b + 0x7FFFu + ((b >> 16) & 1u)) >> 16;   // RNE
    return (unsigned short)r;
}
__device__ __forceinline__ float bf2f(unsigned short u) {
    return __uint_as_float(((unsigned int)u) << 16);
}

// ---------------- convert x to bf16 ------------------------------------------
__global__ __launch_bounds__(256) void cvt_x_kernel(
    const float4* __restrict__ x, ushort4* __restrict__ xb, int n4)
{
    int i = blockIdx.x * 256 + threadIdx.x;
    if (i >= n4) return;
    float4 v = x[i];
    ushort4 o;
    o.x = f2bf(v.x); o.y = f2bf(v.y); o.z = f2bf(v.z); o.w = f2bf(v.w);
    xb[i] = o;
}

// ---------------- convert + transpose weights --------------------------------
__global__ __launch_bounds__(256) void cvt_w_kernel(
    const float* __restrict__ W0, const float* __restrict__ W1,
    const float* __restrict__ W2, unsigned short* __restrict__ wbT)
{
    int z = blockIdx.y;
    const float* W = (z == 0) ? W0 : (z == 1) ? W1 : W2;
    int n = blockIdx.x;           // output row of wbT = column of W
    int k = threadIdx.x;
    wbT[(size_t)z * 65536 + (size_t)n * 256 + k] = f2bf(W[(size_t)k * 256 + n]);
}

// ---------------- fused MFMA GEMM: BM=32, BN=256, all 3 weights --------------
// frag maps (verified): A: lane l elem i -> A[l%16][8*(l/16)+i]
//                       B: lane l elem i -> B[8*(l/16)+i][l%16]
//                       C: lane l reg r  -> C[4*(l/16)+r][l%16]
// Wave w covers cols w*64..w*64+63; all waves share rows m0..m0+31.
__global__ __launch_bounds__(256) void gemm_fused_kernel(
    const unsigned short* __restrict__ xb, const unsigned short* __restrict__ wbT,
    const float* __restrict__ att_l, const float* __restrict__ att_u,
    unsigned short* __restrict__ xml, unsigned short* __restrict__ xmu,
    float* __restrict__ out,
    float* __restrict__ al, float* __restrict__ bl,
    float* __restrict__ au, float* __restrict__ bu, int M)
{
    const int tid = threadIdx.x;
    const int w = tid >> 6, lane = tid & 63;
    const int r16 = lane & 15, g = lane >> 4;
    const int m0 = blockIdx.x * 32;
    const int n0 = w * 64;

    const int ar0 = min(m0 + r16, M - 1);
    const int ar1 = min(m0 + 16 + r16, M - 1);
    const unsigned short* pa0 = xb + (size_t)ar0 * 256 + 8 * g;
    const unsigned short* pa1 = xb + (size_t)ar1 * 256 + 8 * g;
    const unsigned short* pb  = wbT + (size_t)(n0 + r16) * 256 + 8 * g;

    f32x4 acc[3][2][4];   // [z][mf][nf]
    #pragma unroll
    for (int z = 0; z < 3; ++z)
        #pragma unroll
        for (int mf = 0; mf < 2; ++mf)
            #pragma unroll
            for (int nf = 0; nf < 4; ++nf)
                acc[z][mf][nf] = (f32x4){0.f, 0.f, 0.f, 0.f};

    #pragma unroll
    for (int kt = 0; kt < 256; kt += 32) {
        short8 a0 = *reinterpret_cast<const short8*>(pa0 + kt);
        short8 a1 = *reinterpret_cast<const short8*>(pa1 + kt);
        #pragma unroll
        for (int z = 0; z < 3; ++z) {
            #pragma unroll
            for (int nf = 0; nf < 4; ++nf) {
                short8 bf = *reinterpret_cast<const short8*>(
                    pb + (size_t)z * 65536 + (size_t)nf * 16 * 256 + kt);
                acc[z][0][nf] = __builtin_amdgcn_mfma_f32_16x16x32_bf16(a0, bf, acc[z][0][nf], 0, 0, 0);
                acc[z][1][nf] = __builtin_amdgcn_mfma_f32_16x16x32_bf16(a1, bf, acc[z][1][nf], 0, 0, 0);
            }
        }
    }

    // ---- store xm (bf16) and skip path (fp32) ----
    #pragma unroll
    for (int mf = 0; mf < 2; ++mf)
        #pragma unroll
        for (int r = 0; r < 4; ++r) {
            int row = m0 + mf * 16 + g * 4 + r;
            if (row < M) {
                #pragma unroll
                for (int nf = 0; nf < 4; ++nf) {
                    int col = n0 + nf * 16 + r16;
                    xml[(size_t)row * 256 + col] = f2bf(acc[0][mf][nf][r]);
                    xmu[(size_t)row * 256 + col] = f2bf(acc[1][mf][nf][r]);
                    out[(size_t)row * 256 + col] = acc[2][mf][nf][r] * EPSV;
                }
            }
        }

    // ---- att partial dots + reduce: a = xm.att[:256], b = xm.att[256:] ----
    // per lane, per (z,h): attv[nf] = att_z[h*256 + n0 + nf*16 + r16]
    float attv[2][2][4];
    #pragma unroll
    for (int h = 0; h < 2; ++h)
        #pragma unroll
        for (int nf = 0; nf < 4; ++nf) {
            int c = h * 256 + n0 + nf * 16 + r16;
            attv[0][h][nf] = att_l[c];
            attv[1][h][nf] = att_u[c];
        }

    __shared__ float red[4][32][4];   // [wave][row][a_l,b_l,a_u,b_u]
    #pragma unroll
    for (int mf = 0; mf < 2; ++mf)
        #pragma unroll
        for (int r = 0; r < 4; ++r) {
            float p[4];
            #pragma unroll
            for (int z = 0; z < 2; ++z)
                #pragma unroll
                for (int h = 0; h < 2; ++h) {
                    float s = 0.f;
                    #pragma unroll
                    for (int nf = 0; nf < 4; ++nf)
                        s += acc[z][mf][nf][r] * attv[z][h][nf];
                    p[z * 2 + h] = s;
                }
            // reduce across the 16 lanes of this g-group (xor bits 0..3)
            #pragma unroll
            for (int off = 1; off < 16; off <<= 1)
                #pragma unroll
                for (int c = 0; c < 4; ++c)
                    p[c] += __shfl_xor(p[c], off);
            if (r16 == 0) {
                int row_loc = mf * 16 + g * 4 + r;
                red[w][row_loc][0] = p[0];
                red[w][row_loc][1] = p[1];
                red[w][row_loc][2] = p[2];
                red[w][row_loc][3] = p[3];
            }
        }
    __syncthreads();
    if (tid < 128) {
        int row_loc = tid >> 2, comp = tid & 3;
        int row = m0 + row_loc;
        if (row < M) {
            float s = red[0][row_loc][comp] + red[1][row_loc][comp]
                    + red[2][row_loc][comp] + red[3][row_loc][comp];
            float* dst = (comp == 0) ? al : (comp == 1) ? bl : (comp == 2) ? au : bu;
            dst[row] = s;
        }
    }
}

// ---------------- CSR build: histogram with rank ------------------------------
__global__ __launch_bounds__(256) void hist_kernel(
    const int* __restrict__ il, const int* __restrict__ iu,
    int* __restrict__ cl, int* __restrict__ cu,
    int* __restrict__ rkl, int* __restrict__ rku)
{
    int e = blockIdx.x * 256 + threadIdx.x;
    if (e >= N_EDGES) return;
    rkl[e] = atomicAdd(&cl[il[e]], 1);
    rku[e] = atomicAdd(&cu[iu[e]], 1);
}

// ---------------- 3-phase scan -----------------------------------------------
__global__ __launch_bounds__(1024) void scan_local_kernel(
    const int* __restrict__ cnt0, int* __restrict__ ro0,
    const int* __restrict__ cnt1, int* __restrict__ ro1,
    int* __restrict__ bsum, int n)
{
    int c = blockIdx.y;
    const int* cnt = c ? cnt1 : cnt0;
    int* ro = c ? ro1 : ro0;
    __shared__ int sm[1024];
    int tid = threadIdx.x;
    int i = blockIdx.x * 1024 + tid;
    int v = (i < n) ? cnt[i] : 0;
    sm[tid] = v;
    __syncthreads();
    #pragma unroll
    for (int off = 1; off < 1024; off <<= 1) {
        int t = (tid >= off) ? sm[tid - off] : 0;
        __syncthreads();
        sm[tid] += t;
        __syncthreads();
    }
    if (i < n) ro[i] = sm[tid] - v;                 // local exclusive
    if (tid == 1023) bsum[c * 64 + blockIdx.x] = sm[1023];
}

__global__ __launch_bounds__(128) void scan_bsum_kernel(int* __restrict__ bsum, int nb)
{
    int c = threadIdx.x >> 6, lane = threadIdx.x & 63;
    int v = (lane < nb) ? bsum[c * 64 + lane] : 0;
    int orig = v;
    #pragma unroll
    for (int off = 1; off < 64; off <<= 1) {
        int t = __shfl_up(v, off);
        if (lane >= off) v += t;
    }
    if (lane < nb) bsum[c * 64 + lane] = v - orig;  // exclusive block offsets
}

__global__ __launch_bounds__(256) void scan_apply_kernel(
    int* __restrict__ ro0, int* __restrict__ ro1,
    const int* __restrict__ bsum, int n)
{
    int c = blockIdx.y;
    int* ro = c ? ro1 : ro0;
    int i = blockIdx.x * 256 + threadIdx.x;
    if (i < n) ro[i] += bsum[c * 64 + (i >> 10)];
    if (i == 0) ro[n] = N_EDGES;
}

// ---------------- CSR build: scatter (rank-based, no atomics) -----------------
__global__ __launch_bounds__(256) void scatter_kernel(
    const int* __restrict__ il, const float* __restrict__ vl,
    const int* __restrict__ rol, const int* __restrict__ rkl, int2* __restrict__ egl,
    const int* __restrict__ iu, const float* __restrict__ vu,
    const int* __restrict__ rou, const int* __restrict__ rku, int2* __restrict__ egu)
{
    int e = blockIdx.x * 256 + threadIdx.x;
    if (e >= N_EDGES) return;
    int2 p; p.x = il[N_EDGES + e]; p.y = __float_as_int(vl[e]);
    egl[rol[il[e]] + rkl[e]] = p;
    int2 q; q.x = iu[N_EDGES + e]; q.y = __float_as_int(vu[e]);
    egu[rou[iu[e]] + rku[e]] = q;
}

// ---------------- fused gather + softmax + skip + relu -----------------------
__device__ __forceinline__ float wave_sum(float v) {
    #pragma unroll
    for (int off = 32; off; off >>= 1) v += __shfl_xor(v, off);
    return v;
}

__device__ __forceinline__ void pv_accum(
    int lane, float invs, float evl, int srcl, int t0, int m,
    const unsigned short* __restrict__ xm, float4& acc)
{
    int t = t0;
    for (; t + 2 <= m; t += 2) {
        float w0 = __shfl(evl, t) * invs;
        int   s0 = __shfl(srcl, t);
        float w1 = __shfl(evl, t + 1) * invs;
        int   s1 = __shfl(srcl, t + 1);
        ushort4 u0 = *reinterpret_cast<const ushort4*>(xm + (size_t)s0 * 256 + lane * 4);
        ushort4 u1 = *reinterpret_cast<const ushort4*>(xm + (size_t)s1 * 256 + lane * 4);
        acc.x += w0 * bf2f(u0.x) + w1 * bf2f(u1.x);
        acc.y += w0 * bf2f(u0.y) + w1 * bf2f(u1.y);
        acc.z += w0 * bf2f(u0.z) + w1 * bf2f(u1.z);
        acc.w += w0 * bf2f(u0.w) + w1 * bf2f(u1.w);
    }
    if (t < m) {
        float w0 = __shfl(evl, t) * invs;
        int   s0 = __shfl(srcl, t);
        ushort4 u0 = *reinterpret_cast<const ushort4*>(xm + (size_t)s0 * 256 + lane * 4);
        acc.x += w0 * bf2f(u0.x);
        acc.y += w0 * bf2f(u0.y);
        acc.z += w0 * bf2f(u0.z);
        acc.w += w0 * bf2f(u0.w);
    }
}

__device__ __forceinline__ void conv_accum(
    int node, int lane,
    const int* __restrict__ ro, const int2* __restrict__ eg,
    const float* __restrict__ a, const float* __restrict__ b,
    const unsigned short* __restrict__ xm, float4& acc)
{
    int rs = ro[node], re = ro[node + 1];
    int deg = re - rs;
    if (deg <= 0) return;
    float ai = a[node];
    if (deg <= 64) {
        float evl = 0.f; int srcl = 0;
        if (lane < deg) {
            int2 p = eg[rs + lane];
            srcl = p.x;
            float xv = ai + b[srcl];
            float sc = (xv > 0.f) ? xv : (expf(xv) - 1.f);
            evl = expf(sc * __int_as_float(p.y));
        }
        float invs = 1.f / wave_sum(evl);
        pv_accum(lane, invs, evl, srcl, 0, deg, xm, acc);
    } else {
        float s = 0.f;
        for (int c = rs; c < re; c += 64) {
            int m = min(64, re - c);
            float evl = 0.f;
            if (lane < m) {
                int2 p = eg[c + lane];
                float xv = ai + b[p.x];
                float sc = (xv > 0.f) ? xv : (expf(xv) - 1.f);
                evl = expf(sc * __int_as_float(p.y));
            }
            s += wave_sum(evl);
        }
        float invs = 1.f / s;
        for (int c = rs; c < re; c += 64) {
            int m = min(64, re - c);
            float evl = 0.f; int srcl = 0;
            if (lane < m) {
                int2 p = eg[c + lane];
                srcl = p.x;
                float xv = ai + b[srcl];
                float sc = (xv > 0.f) ? xv : (expf(xv) - 1.f);
                evl = expf(sc * __int_as_float(p.y));
            }
            pv_accum(lane, invs, evl, srcl, 0, m, xm, acc);
        }
    }
}

__global__ __launch_bounds__(256) void gather_kernel(
    const int* __restrict__ rol, const int2* __restrict__ egl,
    const float* __restrict__ al, const float* __restrict__ bl,
    const unsigned short* __restrict__ xml,
    const int* __restrict__ rou, const int2* __restrict__ egu,
    const float* __restrict__ au, const float* __restrict__ bu,
    const unsigned short* __restrict__ xmu,
    float4* __restrict__ out)
{
    int node = (int)((blockIdx.x * 256 + threadIdx.x) >> 6);
    int lane = threadIdx.x & 63;
    if (node >= N_NODES) return;
    float4 acc = make_float4(0.f, 0.f, 0.f, 0.f);
    conv_accum(node, lane, rol, egl, al, bl, xml, acc);
    conv_accum(node, lane, rou, egu, au, bu, xmu, acc);
    float4 xw = out[(size_t)node * 64 + lane];
    acc.x = fmaxf(acc.x + xw.x, 0.f);
    acc.y = fmaxf(acc.y + xw.y, 0.f);
    acc.z = fmaxf(acc.z + xw.z, 0.f);
    acc.w = fmaxf(acc.w + xw.w, 0.f);
    out[(size_t)node * 64 + lane] = acc;
}

extern "C" void kernel_launch(void* const* d_in, const int* in_sizes, int n_in,
                              void* d_out, int out_size, void* d_ws, size_t ws_size,
                              hipStream_t stream)
{
    (void)in_sizes; (void)n_in; (void)out_size; (void)ws_size;
    const float* x        = (const float*)d_in[0];
    const int*   low_idx  = (const int*)  d_in[1];
    const float* low_vals = (const float*)d_in[2];
    const int*   up_idx   = (const int*)  d_in[3];
    const float* up_vals  = (const float*)d_in[4];
    const float* W_lower  = (const float*)d_in[5];
    const float* att_low  = (const float*)d_in[6];
    const float* W_upper  = (const float*)d_in[7];
    const float* att_up   = (const float*)d_in[8];
    const float* W_lin    = (const float*)d_in[9];
    float* out = (float*)d_out;

    char* ws = (char*)d_ws;
    size_t off = 0;
    auto alloc = [&](size_t bytes) {
        void* p = ws + off;
        off += (bytes + 255) & ~(size_t)255;
        return p;
    };
    unsigned short* xb     = (unsigned short*)alloc((size_t)N_NODES * D * 2);
    unsigned short* wbT    = (unsigned short*)alloc((size_t)3 * 256 * 256 * 2);
    unsigned short* xm_low = (unsigned short*)alloc((size_t)N_NODES * D * 2);
    unsigned short* xm_up  = (unsigned short*)alloc((size_t)N_NODES * D * 2);
    float* a_low  = (float*)alloc(N_NODES * 4);
    float* b_low  = (float*)alloc(N_NODES * 4);
    float* a_up   = (float*)alloc(N_NODES * 4);
    float* b_up   = (float*)alloc(N_NODES * 4);
    int* zero_blk = (int*)alloc(2 * N_NODES * 4);   // cnt_l | cnt_u
    int* cnt_low = zero_blk;
    int* cnt_up  = zero_blk + N_NODES;
    int* rk_low  = (int*)alloc((size_t)N_EDGES * 4);
    int* rk_up   = (int*)alloc((size_t)N_EDGES * 4);
    int* ro_low  = (int*)alloc((N_NODES + 1) * 4);
    int* ro_up   = (int*)alloc((N_NODES + 1) * 4);
    int* bsum    = (int*)alloc(2 * 64 * 4);
    int2* eg_low = (int2*)alloc((size_t)N_EDGES * 8);
    int2* eg_up  = (int2*)alloc((size_t)N_EDGES * 8);

    hipMemsetAsync(zero_blk, 0, 2 * N_NODES * 4, stream);

    // 0) casts
    int n4 = N_NODES * D / 4;
    cvt_x_kernel<<<(n4 + 255) / 256, 256, 0, stream>>>(
        (const float4*)x, (ushort4*)xb, n4);
    dim3 wgrid(256, 3);
    cvt_w_kernel<<<wgrid, 256, 0, stream>>>(W_lower, W_upper, W_lin, wbT);

    // 1) fused MFMA GEMM (+att epilogue, skip path straight into d_out)
    int gemmblocks = (N_NODES + 31) / 32;
    gemm_fused_kernel<<<gemmblocks, 256, 0, stream>>>(
        xb, wbT, att_low, att_up, xm_low, xm_up, out,
        a_low, b_low, a_up, b_up, N_NODES);

    // 2) CSR build
    int eblocks = (N_EDGES + 255) / 256;
    hist_kernel<<<eblocks, 256, 0, stream>>>(low_idx, up_idx, cnt_low, cnt_up,
                                             rk_low, rk_up);
    dim3 sgrid((N_NODES + 1023) / 1024, 2);
    scan_local_kernel<<<sgrid, 1024, 0, stream>>>(cnt_low, ro_low, cnt_up, ro_up,
                                                  bsum, N_NODES);
    scan_bsum_kernel<<<1, 128, 0, stream>>>(bsum, (N_NODES + 1023) / 1024);
    dim3 agrid((N_NODES + 255) / 256, 2);
    scan_apply_kernel<<<agrid, 256, 0, stream>>>(ro_low, ro_up, bsum, N_NODES);
    scatter_kernel<<<eblocks, 256, 0, stream>>>(
        low_idx, low_vals, ro_low, rk_low, eg_low,
        up_idx,  up_vals,  ro_up,  rk_up,  eg_up);

    // 3) fused gather + softmax + skip + relu
    int gblocks = (N_NODES + 3) / 4;
    gather_kernel<<<gblocks, 256, 0, stream>>>(
        ro_low, eg_low, a_low, b_low, xm_low,
        ro_up,  eg_up,  a_up,  b_up,  xm_up,
        (float4*)out);
}

// Round 6
// 439.399 us; speedup vs baseline: 4.0532x; 1.1005x over previous
//
#include <hip/hip_runtime.h>
#include <hip/hip_bf16.h>

// CANLayer round 6: LDS-staged-B MFMA GEMM (z in grid), fused prep kernel.
//   K0  memset  : zero cnt_l|cnt_u
//   K1  prep    : cvt_x (bf16) + cvt_w (bf16,T) + hist/rank   [grid-stride]
//   K2  gemm    : per block (128 rows x 64 cols x 1 weight):
//                 B fragment strip staged in LDS (32KB, conflict-free),
//                 A fragments direct from global (L3-resident).
//   K3  att     : a/b scalars for both convs (one dispatch)
//   K4  scan    : 3-phase parallel exclusive scan -> ro
//   K5  scatter : eg[ro[tgt]+rank[e]] = {src, val}   (no atomics)
//   K6  gather  : per-node wave softmax-gather (bf16 rows) + skip + relu
// softmax max-subtraction skipped: invariant, v bounded in (-1,~3).

constexpr int N_NODES = 50000;
constexpr int N_EDGES = 800000;
constexpr int D = 256;
constexpr float EPSV = 1.0f + 1e-06f;

typedef __attribute__((ext_vector_type(8))) short short8;
typedef __attribute__((ext_vector_type(4))) float f32x4;

__device__ __forceinline__ unsigned short f2bf(float f) {
    unsigned int b = __float_as_uint(f);
    unsigned int r = (b + 0x7FFFu + ((b >> 16) & 1u)) >> 16;   // RNE
    return (unsigned short)r;
}
__device__ __forceinline__ float bf2f(unsigned short u) {
    return __uint_as_float(((unsigned int)u) << 16);
}

// ---------------- prep: cvt_x + cvt_w + hist (independent phases) ------------
__global__ __launch_bounds__(256) void prep_kernel(
    const float4* __restrict__ x, ushort4* __restrict__ xb, int n4,
    const float* __restrict__ W0, const float* __restrict__ W1,
    const float* __restrict__ W2, unsigned short* __restrict__ wbT,
    const int* __restrict__ il, const int* __restrict__ iu,
    int* __restrict__ cl, int* __restrict__ cu,
    int* __restrict__ rkl, int* __restrict__ rku)
{
    int gid = blockIdx.x * 256 + threadIdx.x;
    int gsz = gridDim.x * 256;
    // x -> bf16
    for (int i = gid; i < n4; i += gsz) {
        float4 v = x[i];
        ushort4 o;
        o.x = f2bf(v.x); o.y = f2bf(v.y); o.z = f2bf(v.z); o.w = f2bf(v.w);
        xb[i] = o;
    }
    // W -> bf16 transposed: wbT[z][n][k] = W_z[k][n]  (read-coalesced)
    for (int i = gid; i < 3 * 65536; i += gsz) {
        int z = i >> 16, rem = i & 65535;
        int k = rem >> 8, n = rem & 255;
        const float* W = (z == 0) ? W0 : (z == 1) ? W1 : W2;
        wbT[(size_t)z * 65536 + (size_t)n * 256 + k] = f2bf(W[(size_t)k * 256 + n]);
    }
    // histogram + rank
    for (int e = gid; e < N_EDGES; e += gsz) {
        rkl[e] = atomicAdd(&cl[il[e]], 1);
        rku[e] = atomicAdd(&cu[iu[e]], 1);
    }
}

// ---------------- MFMA GEMM: BM=128, BN=64, B strip in LDS -------------------
// frag maps (verified): A: lane l elem i -> A[l%16][8*(l/16)+i]
//                       B: lane l elem i -> B[8*(l/16)+i][l%16]
//                       C: lane l reg r  -> C[4*(l/16)+r][l%16]
__global__ __launch_bounds__(256) void gemm_lds_kernel(
    const unsigned short* __restrict__ xb, const unsigned short* __restrict__ wbT,
    unsigned short* __restrict__ xml, unsigned short* __restrict__ xmu,
    float* __restrict__ out, int M)
{
    const int wz = blockIdx.z;
    const int tid = threadIdx.x;
    const int w = tid >> 6, lane = tid & 63;
    const int r16 = lane & 15, g = lane >> 4;
    const int m0 = blockIdx.x * 128 + w * 32;
    const int n0 = blockIdx.y * 64;

    // stage B fragment strip: bs[kt][nf][lane] = wbT[wz][n0+nf*16+(l&15)][kt*32+8*(l>>4) ..+8]
    __shared__ short8 bs[8][4][64];
    {
        const unsigned short* wb = wbT + (size_t)wz * 65536;
        #pragma unroll
        for (int c = tid; c < 2048; c += 256) {
            int kt = c >> 8, nf = (c >> 6) & 3, l = c & 63;
            bs[kt][nf][l] = *reinterpret_cast<const short8*>(
                wb + (size_t)(n0 + nf * 16 + (l & 15)) * 256 + kt * 32 + 8 * (l >> 4));
        }
    }
    __syncthreads();

    const int ar0 = min(m0 + r16, M - 1);
    const int ar1 = min(m0 + 16 + r16, M - 1);
    const unsigned short* pa0 = xb + (size_t)ar0 * 256 + 8 * g;
    const unsigned short* pa1 = xb + (size_t)ar1 * 256 + 8 * g;

    f32x4 acc[2][4];
    #pragma unroll
    for (int mf = 0; mf < 2; ++mf)
        #pragma unroll
        for (int nf = 0; nf < 4; ++nf)
            acc[mf][nf] = (f32x4){0.f, 0.f, 0.f, 0.f};

    #pragma unroll
    for (int kt = 0; kt < 8; ++kt) {
        short8 a0 = *reinterpret_cast<const short8*>(pa0 + kt * 32);
        short8 a1 = *reinterpret_cast<const short8*>(pa1 + kt * 32);
        #pragma unroll
        for (int nf = 0; nf < 4; ++nf) {
            short8 bf = bs[kt][nf][lane];
            acc[0][nf] = __builtin_amdgcn_mfma_f32_16x16x32_bf16(a0, bf, acc[0][nf], 0, 0, 0);
            acc[1][nf] = __builtin_amdgcn_mfma_f32_16x16x32_bf16(a1, bf, acc[1][nf], 0, 0, 0);
        }
    }

    if (wz < 2) {
        unsigned short* dst = wz ? xmu : xml;
        #pragma unroll
        for (int mf = 0; mf < 2; ++mf)
            #pragma unroll
            for (int r = 0; r < 4; ++r) {
                int row = m0 + mf * 16 + g * 4 + r;
                if (row < M) {
                    #pragma unroll
                    for (int nf = 0; nf < 4; ++nf)
                        dst[(size_t)row * 256 + n0 + nf * 16 + r16] = f2bf(acc[mf][nf][r]);
                }
            }
    } else {
        #pragma unroll
        for (int mf = 0; mf < 2; ++mf)
            #pragma unroll
            for (int r = 0; r < 4; ++r) {
                int row = m0 + mf * 16 + g * 4 + r;
                if (row < M) {
                    #pragma unroll
                    for (int nf = 0; nf < 4; ++nf)
                        out[(size_t)row * 256 + n0 + nf * 16 + r16] = acc[mf][nf][r] * EPSV;
                }
            }
    }
}

// ---------------- att scalars for both convs (one wave per node) -------------
__global__ __launch_bounds__(256) void att_both_kernel(
    const unsigned short* __restrict__ xml, const unsigned short* __restrict__ xmu,
    const float* __restrict__ att_l, const float* __restrict__ att_u,
    float* __restrict__ al, float* __restrict__ bl,
    float* __restrict__ au, float* __restrict__ bu, int n)
{
    int node = (int)((blockIdx.x * 256 + threadIdx.x) >> 6);
    int lane = threadIdx.x & 63;
    if (node >= n) return;
    int o = lane * 4;
    ushort4 ul = *reinterpret_cast<const ushort4*>(xml + (size_t)node * 256 + o);
    ushort4 uu = *reinterpret_cast<const ushort4*>(xmu + (size_t)node * 256 + o);
    float l0 = bf2f(ul.x), l1 = bf2f(ul.y), l2 = bf2f(ul.z), l3 = bf2f(ul.w);
    float u0 = bf2f(uu.x), u1 = bf2f(uu.y), u2 = bf2f(uu.z), u3 = bf2f(uu.w);
    float p[4];
    p[0] = l0 * att_l[o] + l1 * att_l[o + 1] + l2 * att_l[o + 2] + l3 * att_l[o + 3];
    p[1] = l0 * att_l[D + o] + l1 * att_l[D + o + 1] + l2 * att_l[D + o + 2] + l3 * att_l[D + o + 3];
    p[2] = u0 * att_u[o] + u1 * att_u[o + 1] + u2 * att_u[o + 2] + u3 * att_u[o + 3];
    p[3] = u0 * att_u[D + o] + u1 * att_u[D + o + 1] + u2 * att_u[D + o + 2] + u3 * att_u[D + o + 3];
    #pragma unroll
    for (int off = 32; off; off >>= 1)
        #pragma unroll
        for (int c = 0; c < 4; ++c)
            p[c] += __shfl_down(p[c], off);
    if (lane == 0) { al[node] = p[0]; bl[node] = p[1]; au[node] = p[2]; bu[node] = p[3]; }
}

// ---------------- 3-phase scan -----------------------------------------------
__global__ __launch_bounds__(1024) void scan_local_kernel(
    const int* __restrict__ cnt0, int* __restrict__ ro0,
    const int* __restrict__ cnt1, int* __restrict__ ro1,
    int* __restrict__ bsum, int n)
{
    int c = blockIdx.y;
    const int* cnt = c ? cnt1 : cnt0;
    int* ro = c ? ro1 : ro0;
    __shared__ int sm[1024];
    int tid = threadIdx.x;
    int i = blockIdx.x * 1024 + tid;
    int v = (i < n) ? cnt[i] : 0;
    sm[tid] = v;
    __syncthreads();
    #pragma unroll
    for (int off = 1; off < 1024; off <<= 1) {
        int t = (tid >= off) ? sm[tid - off] : 0;
        __syncthreads();
        sm[tid] += t;
        __syncthreads();
    }
    if (i < n) ro[i] = sm[tid] - v;                 // local exclusive
    if (tid == 1023) bsum[c * 64 + blockIdx.x] = sm[1023];
}

__global__ __launch_bounds__(128) void scan_bsum_kernel(int* __restrict__ bsum, int nb)
{
    int c = threadIdx.x >> 6, lane = threadIdx.x & 63;
    int v = (lane < nb) ? bsum[c * 64 + lane] : 0;
    int orig = v;
    #pragma unroll
    for (int off = 1; off < 64; off <<= 1) {
        int t = __shfl_up(v, off);
        if (lane >= off) v += t;
    }
    if (lane < nb) bsum[c * 64 + lane] = v - orig;  // exclusive block offsets
}

__global__ __launch_bounds__(256) void scan_apply_kernel(
    int* __restrict__ ro0, int* __restrict__ ro1,
    const int* __restrict__ bsum, int n)
{
    int c = blockIdx.y;
    int* ro = c ? ro1 : ro0;
    int i = blockIdx.x * 256 + threadIdx.x;
    if (i < n) ro[i] += bsum[c * 64 + (i >> 10)];
    if (i == 0) ro[n] = N_EDGES;
}

// ---------------- CSR build: scatter (rank-based, no atomics) -----------------
__global__ __launch_bounds__(256) void scatter_kernel(
    const int* __restrict__ il, const float* __restrict__ vl,
    const int* __restrict__ rol, const int* __restrict__ rkl, int2* __restrict__ egl,
    const int* __restrict__ iu, const float* __restrict__ vu,
    const int* __restrict__ rou, const int* __restrict__ rku, int2* __restrict__ egu)
{
    int e = blockIdx.x * 256 + threadIdx.x;
    if (e >= N_EDGES) return;
    int2 p; p.x = il[N_EDGES + e]; p.y = __float_as_int(vl[e]);
    egl[rol[il[e]] + rkl[e]] = p;
    int2 q; q.x = iu[N_EDGES + e]; q.y = __float_as_int(vu[e]);
    egu[rou[iu[e]] + rku[e]] = q;
}

// ---------------- fused gather + softmax + skip + relu -----------------------
__device__ __forceinline__ float wave_sum(float v) {
    #pragma unroll
    for (int off = 32; off; off >>= 1) v += __shfl_xor(v, off);
    return v;
}

__device__ __forceinline__ void pv_accum(
    int lane, float invs, float evl, int srcl, int m,
    const unsigned short* __restrict__ xm, float4& acc)
{
    int t = 0;
    for (; t + 2 <= m; t += 2) {
        float w0 = __shfl(evl, t) * invs;
        int   s0 = __shfl(srcl, t);
        float w1 = __shfl(evl, t + 1) * invs;
        int   s1 = __shfl(srcl, t + 1);
        ushort4 u0 = *reinterpret_cast<const ushort4*>(xm + (size_t)s0 * 256 + lane * 4);
        ushort4 u1 = *reinterpret_cast<const ushort4*>(xm + (size_t)s1 * 256 + lane * 4);
        acc.x += w0 * bf2f(u0.x) + w1 * bf2f(u1.x);
        acc.y += w0 * bf2f(u0.y) + w1 * bf2f(u1.y);
        acc.z += w0 * bf2f(u0.z) + w1 * bf2f(u1.z);
        acc.w += w0 * bf2f(u0.w) + w1 * bf2f(u1.w);
    }
    if (t < m) {
        float w0 = __shfl(evl, t) * invs;
        int   s0 = __shfl(srcl, t);
        ushort4 u0 = *reinterpret_cast<const ushort4*>(xm + (size_t)s0 * 256 + lane * 4);
        acc.x += w0 * bf2f(u0.x);
        acc.y += w0 * bf2f(u0.y);
        acc.z += w0 * bf2f(u0.z);
        acc.w += w0 * bf2f(u0.w);
    }
}

__device__ __forceinline__ void conv_accum(
    int node, int lane,
    const int* __restrict__ ro, const int2* __restrict__ eg,
    const float* __restrict__ a, const float* __restrict__ b,
    const unsigned short* __restrict__ xm, float4& acc)
{
    int rs = ro[node], re = ro[node + 1];
    int deg = re - rs;
    if (deg <= 0) return;
    float ai = a[node];
    if (deg <= 64) {
        float evl = 0.f; int srcl = 0;
        if (lane < deg) {
            int2 p = eg[rs + lane];
            srcl = p.x;
            float xv = ai + b[srcl];
            float sc = (xv > 0.f) ? xv : (expf(xv) - 1.f);
            evl = expf(sc * __int_as_float(p.y));
        }
        float invs = 1.f / wave_sum(evl);
        pv_accum(lane, invs, evl, srcl, deg, xm, acc);
    } else {
        float s = 0.f;
        for (int c = rs; c < re; c += 64) {
            int m = min(64, re - c);
            float evl = 0.f;
            if (lane < m) {
                int2 p = eg[c + lane];
                float xv = ai + b[p.x];
                float sc = (xv > 0.f) ? xv : (expf(xv) - 1.f);
                evl = expf(sc * __int_as_float(p.y));
            }
            s += wave_sum(evl);
        }
        float invs = 1.f / s;
        for (int c = rs; c < re; c += 64) {
            int m = min(64, re - c);
            float evl = 0.f; int srcl = 0;
            if (lane < m) {
                int2 p = eg[c + lane];
                srcl = p.x;
                float xv = ai + b[srcl];
                float sc = (xv > 0.f) ? xv : (expf(xv) - 1.f);
                evl = expf(sc * __int_as_float(p.y));
            }
            pv_accum(lane, invs, evl, srcl, m, xm, acc);
        }
    }
}

__global__ __launch_bounds__(256) void gather_kernel(
    const int* __restrict__ rol, const int2* __restrict__ egl,
    const float* __restrict__ al, const float* __restrict__ bl,
    const unsigned short* __restrict__ xml,
    const int* __restrict__ rou, const int2* __restrict__ egu,
    const float* __restrict__ au, const float* __restrict__ bu,
    const unsigned short* __restrict__ xmu,
    float4* __restrict__ out)
{
    int node = (int)((blockIdx.x * 256 + threadIdx.x) >> 6);
    int lane = threadIdx.x & 63;
    if (node >= N_NODES) return;
    float4 acc = make_float4(0.f, 0.f, 0.f, 0.f);
    conv_accum(node, lane, rol, egl, al, bl, xml, acc);
    conv_accum(node, lane, rou, egu, au, bu, xmu, acc);
    float4 xw = out[(size_t)node * 64 + lane];
    acc.x = fmaxf(acc.x + xw.x, 0.f);
    acc.y = fmaxf(acc.y + xw.y, 0.f);
    acc.z = fmaxf(acc.z + xw.z, 0.f);
    acc.w = fmaxf(acc.w + xw.w, 0.f);
    out[(size_t)node * 64 + lane] = acc;
}

extern "C" void kernel_launch(void* const* d_in, const int* in_sizes, int n_in,
                              void* d_out, int out_size, void* d_ws, size_t ws_size,
                              hipStream_t stream)
{
    (void)in_sizes; (void)n_in; (void)out_size; (void)ws_size;
    const float* x        = (const float*)d_in[0];
    const int*   low_idx  = (const int*)  d_in[1];
    const float* low_vals = (const float*)d_in[2];
    const int*   up_idx   = (const int*)  d_in[3];
    const float* up_vals  = (const float*)d_in[4];
    const float* W_lower  = (const float*)d_in[5];
    const float* att_low  = (const float*)d_in[6];
    const float* W_upper  = (const float*)d_in[7];
    const float* att_up   = (const float*)d_in[8];
    const float* W_lin    = (const float*)d_in[9];
    float* out = (float*)d_out;

    char* ws = (char*)d_ws;
    size_t off = 0;
    auto alloc = [&](size_t bytes) {
        void* p = ws + off;
        off += (bytes + 255) & ~(size_t)255;
        return p;
    };
    unsigned short* xb     = (unsigned short*)alloc((size_t)N_NODES * D * 2);
    unsigned short* wbT    = (unsigned short*)alloc((size_t)3 * 256 * 256 * 2);
    unsigned short* xm_low = (unsigned short*)alloc((size_t)N_NODES * D * 2);
    unsigned short* xm_up  = (unsigned short*)alloc((size_t)N_NODES * D * 2);
    float* a_low  = (float*)alloc(N_NODES * 4);
    float* b_low  = (float*)alloc(N_NODES * 4);
    float* a_up   = (float*)alloc(N_NODES * 4);
    float* b_up   = (float*)alloc(N_NODES * 4);
    int* zero_blk = (int*)alloc(2 * N_NODES * 4);   // cnt_l | cnt_u
    int* cnt_low = zero_blk;
    int* cnt_up  = zero_blk + N_NODES;
    int* rk_low  = (int*)alloc((size_t)N_EDGES * 4);
    int* rk_up   = (int*)alloc((size_t)N_EDGES * 4);
    int* ro_low  = (int*)alloc((N_NODES + 1) * 4);
    int* ro_up   = (int*)alloc((N_NODES + 1) * 4);
    int* bsum    = (int*)alloc(2 * 64 * 4);
    int2* eg_low = (int2*)alloc((size_t)N_EDGES * 8);
    int2* eg_up  = (int2*)alloc((size_t)N_EDGES * 8);

    hipMemsetAsync(zero_blk, 0, 2 * N_NODES * 4, stream);

    // 1) prep: cvt_x + cvt_w + hist/rank (single dispatch)
    int n4 = N_NODES * D / 4;
    prep_kernel<<<2048, 256, 0, stream>>>(
        (const float4*)x, (ushort4*)xb, n4,
        W_lower, W_upper, W_lin, wbT,
        low_idx, up_idx, cnt_low, cnt_up, rk_low, rk_up);

    // 2) MFMA GEMM with LDS-staged B
    dim3 ggrid((N_NODES + 127) / 128, 4, 3);
    gemm_lds_kernel<<<ggrid, 256, 0, stream>>>(xb, wbT, xm_low, xm_up, out, N_NODES);

    // 3) att scalars (both convs, one dispatch)
    int ablocks = (N_NODES + 3) / 4;
    att_both_kernel<<<ablocks, 256, 0, stream>>>(
        xm_low, xm_up, att_low, att_up, a_low, b_low, a_up, b_up, N_NODES);

    // 4) CSR scan + scatter
    dim3 sgrid((N_NODES + 1023) / 1024, 2);
    scan_local_kernel<<<sgrid, 1024, 0, stream>>>(cnt_low, ro_low, cnt_up, ro_up,
                                                  bsum, N_NODES);
    scan_bsum_kernel<<<1, 128, 0, stream>>>(bsum, (N_NODES + 1023) / 1024);
    dim3 agrid((N_NODES + 255) / 256, 2);
    scan_apply_kernel<<<agrid, 256, 0, stream>>>(ro_low, ro_up, bsum, N_NODES);
    int eblocks = (N_EDGES + 255) / 256;
    scatter_kernel<<<eblocks, 256, 0, stream>>>(
        low_idx, low_vals, ro_low, rk_low, eg_low,
        up_idx,  up_vals,  ro_up,  rk_up,  eg_up);

    // 5) fused gather + softmax + skip + relu
    int gblocks = (N_NODES + 3) / 4;
    gather_kernel<<<gblocks, 256, 0, stream>>>(
        ro_low, eg_low, a_low, b_low, xm_low,
        ro_up,  eg_up,  a_up,  b_up,  xm_up,
        (float4*)out);
}